// Round 1
// baseline (74.696 us; speedup 1.0000x reference)
//
#include <hip/hip_runtime.h>

// SimpleGNN: B=4, N=512, D=128, L=2
// Key algebraic rewrite: sum over j commutes with the (linear) second layer:
//   msg[b,i,:] = (sum_j adj[b,i,j]*relu(ai'[b,i,:]+aj[b,j,:])) @ w2^T
//              + (sum_j adj[b,i,j]) * b2
// where ai' = h @ wi^T + b1, aj = h @ wj^T.
// This avoids the [B,N,N,D] intermediate and the [B*N*N,D]x[D,D] GEMM.

constexpr int Bc = 4, Nc = 512, Dc = 128, Lc = 2;
constexpr int BN = Bc * Nc; // 2048

// --- weight transpose: wiT[l][d][o] = w1[l][o][d], wjT[l][d][o] = w1[l][o][D+d],
//                       w2T[l][d][o] = w2[l][o][d]
__global__ void transpose_w_kernel(const float* __restrict__ w1,
                                   const float* __restrict__ w2,
                                   float* __restrict__ wiT,
                                   float* __restrict__ wjT,
                                   float* __restrict__ w2T) {
    int idx = blockIdx.x * blockDim.x + threadIdx.x;
    if (idx >= Lc * Dc * Dc) return;
    int l = idx / (Dc * Dc);
    int rem = idx - l * Dc * Dc;
    int d = rem / Dc;
    int o = rem - d * Dc;
    wiT[idx] = w1[(l * Dc + o) * (2 * Dc) + d];
    wjT[idx] = w1[(l * Dc + o) * (2 * Dc) + Dc + d];
    w2T[idx] = w2[(l * Dc + o) * Dc + d];
}

// --- first linear: ai'[r][o] = sum_d h[r][d]*wiT[d][o] + b1[o];  aj[r][o] = sum_d h[r][d]*wjT[d][o]
template <int TN>
__global__ __launch_bounds__(128) void gnn_lin1(const float* __restrict__ h,
                                                const float* __restrict__ wiT,
                                                const float* __restrict__ wjT,
                                                const float* __restrict__ b1,
                                                float* __restrict__ ai,
                                                float* __restrict__ aj) {
    __shared__ float hs[TN][Dc];
    const int o = threadIdx.x;
    const int r0 = blockIdx.x * TN;
#pragma unroll
    for (int t = 0; t < TN; ++t) hs[t][o] = h[(r0 + t) * Dc + o];
    __syncthreads();
    float acci[TN], accj[TN];
    const float bo = b1[o];
#pragma unroll
    for (int t = 0; t < TN; ++t) { acci[t] = bo; accj[t] = 0.f; }
    for (int d = 0; d < Dc; d += 4) {
        float wi[4], wj[4];
#pragma unroll
        for (int k = 0; k < 4; ++k) {
            wi[k] = wiT[(d + k) * Dc + o];
            wj[k] = wjT[(d + k) * Dc + o];
        }
#pragma unroll
        for (int t = 0; t < TN; ++t) {
            const float4 hv = *reinterpret_cast<const float4*>(&hs[t][d]);
            acci[t] = fmaf(hv.x, wi[0], acci[t]);
            acci[t] = fmaf(hv.y, wi[1], acci[t]);
            acci[t] = fmaf(hv.z, wi[2], acci[t]);
            acci[t] = fmaf(hv.w, wi[3], acci[t]);
            accj[t] = fmaf(hv.x, wj[0], accj[t]);
            accj[t] = fmaf(hv.y, wj[1], accj[t]);
            accj[t] = fmaf(hv.z, wj[2], accj[t]);
            accj[t] = fmaf(hv.w, wj[3], accj[t]);
        }
    }
#pragma unroll
    for (int t = 0; t < TN; ++t) {
        ai[(r0 + t) * Dc + o] = acci[t];
        aj[(r0 + t) * Dc + o] = accj[t];
    }
}

// --- masked-relu reduction over j:
//   s[r][d]  = sum_j adj[b,i,j] * relu(ai'[r][d] + aj[b,j,d])
//   arow[r]  = sum_j adj[b,i,j]
// 256 threads: tid = half*128 + d; each half handles 256 of the 512 j's.
__global__ __launch_bounds__(256) void gnn_msg(const float* __restrict__ ai,
                                               const float* __restrict__ aj,
                                               const float* __restrict__ adj,
                                               float* __restrict__ s,
                                               float* __restrict__ arow) {
    constexpr int TI = 4;
    __shared__ float adjs[2][128][TI];   // [half][jj][t]
    __shared__ float accred[TI][128];
    __shared__ float red[TI][256];
    const int tid = threadIdx.x;
    const int d = tid & 127;
    const int half = tid >> 7;
    const int r0 = blockIdx.x * TI;
    const int b = r0 / Nc;
    const int i0 = r0 - b * Nc;
    const float* __restrict__ ajb = aj + b * Nc * Dc;
    const float* __restrict__ adjb = adj + (size_t)b * Nc * Nc;

    float x[TI], acc[TI], ps[TI];
#pragma unroll
    for (int t = 0; t < TI; ++t) {
        x[t] = ai[(r0 + t) * Dc + d];
        acc[t] = 0.f;
        ps[t] = 0.f;
    }

    for (int c = 0; c < 2; ++c) {
        const int j0 = half * 256 + c * 128;
        __syncthreads();
#pragma unroll
        for (int t = 0; t < TI; ++t) {
            const float v = adjb[(i0 + t) * Nc + j0 + d];
            adjs[half][d][t] = v;
            ps[t] += v;
        }
        __syncthreads();
#pragma unroll 8
        for (int jj = 0; jj < 128; ++jj) {
            const float v = ajb[(j0 + jj) * Dc + d];
            const float4 a4 = *reinterpret_cast<const float4*>(&adjs[half][jj][0]);
            acc[0] = fmaf(a4.x, fmaxf(x[0] + v, 0.f), acc[0]);
            acc[1] = fmaf(a4.y, fmaxf(x[1] + v, 0.f), acc[1]);
            acc[2] = fmaf(a4.z, fmaxf(x[2] + v, 0.f), acc[2]);
            acc[3] = fmaf(a4.w, fmaxf(x[3] + v, 0.f), acc[3]);
        }
    }

    // combine the two j-halves
    if (half == 1) {
#pragma unroll
        for (int t = 0; t < TI; ++t) accred[t][d] = acc[t];
    }
    __syncthreads();
    if (half == 0) {
#pragma unroll
        for (int t = 0; t < TI; ++t) s[(r0 + t) * Dc + d] = acc[t] + accred[t][d];
    }

    // adj row sums
#pragma unroll
    for (int t = 0; t < TI; ++t) red[t][tid] = ps[t];
    __syncthreads();
    if (tid < TI) {
        float sum = 0.f;
        for (int k = 0; k < 256; ++k) sum += red[tid][k];
        arow[r0 + tid] = sum;
    }
}

// --- second linear + residual:
//   hout[r][o] = hin[r][o] + sum_d s[r][d]*w2T[d][o] + arow[r]*b2[o]
template <int TN>
__global__ __launch_bounds__(128) void gnn_lin2(const float* __restrict__ hin,
                                                const float* __restrict__ s,
                                                const float* __restrict__ arow,
                                                const float* __restrict__ w2T,
                                                const float* __restrict__ b2,
                                                float* __restrict__ hout) {
    __shared__ float ss[TN][Dc];
    const int o = threadIdx.x;
    const int r0 = blockIdx.x * TN;
#pragma unroll
    for (int t = 0; t < TN; ++t) ss[t][o] = s[(r0 + t) * Dc + o];
    __syncthreads();
    float acc[TN];
#pragma unroll
    for (int t = 0; t < TN; ++t) acc[t] = 0.f;
    for (int d = 0; d < Dc; d += 4) {
        float w[4];
#pragma unroll
        for (int k = 0; k < 4; ++k) w[k] = w2T[(d + k) * Dc + o];
#pragma unroll
        for (int t = 0; t < TN; ++t) {
            const float4 sv = *reinterpret_cast<const float4*>(&ss[t][d]);
            acc[t] = fmaf(sv.x, w[0], acc[t]);
            acc[t] = fmaf(sv.y, w[1], acc[t]);
            acc[t] = fmaf(sv.z, w[2], acc[t]);
            acc[t] = fmaf(sv.w, w[3], acc[t]);
        }
    }
    const float b2o = b2[o];
#pragma unroll
    for (int t = 0; t < TN; ++t) {
        hout[(r0 + t) * Dc + o] = hin[(r0 + t) * Dc + o] + acc[t] + arow[r0 + t] * b2o;
    }
}

extern "C" void kernel_launch(void* const* d_in, const int* in_sizes, int n_in,
                              void* d_out, int out_size, void* d_ws, size_t ws_size,
                              hipStream_t stream) {
    const float* node = (const float*)d_in[0];
    const float* adj  = (const float*)d_in[1];
    const float* w1   = (const float*)d_in[2];
    const float* b1   = (const float*)d_in[3];
    const float* w2   = (const float*)d_in[4];
    const float* b2   = (const float*)d_in[5];
    float* out = (float*)d_out;

    float* ws = (float*)d_ws;
    float* wiT  = ws; ws += Lc * Dc * Dc;
    float* wjT  = ws; ws += Lc * Dc * Dc;
    float* w2T  = ws; ws += Lc * Dc * Dc;
    float* ai   = ws; ws += BN * Dc;
    float* aj   = ws; ws += BN * Dc;
    float* sbuf = ws; ws += BN * Dc;
    float* arow = ws; ws += BN;
    float* h1   = ws; ws += BN * Dc;

    transpose_w_kernel<<<(Lc * Dc * Dc + 255) / 256, 256, 0, stream>>>(w1, w2, wiT, wjT, w2T);

    for (int l = 0; l < Lc; ++l) {
        const float* hin = (l == 0) ? node : h1;
        float* hout = (l == Lc - 1) ? out : h1;
        const float* wiTl = wiT + l * Dc * Dc;
        const float* wjTl = wjT + l * Dc * Dc;
        const float* w2Tl = w2T + l * Dc * Dc;
        const float* b1l = b1 + l * Dc;
        const float* b2l = b2 + l * Dc;

        gnn_lin1<4><<<BN / 4, 128, 0, stream>>>(hin, wiTl, wjTl, b1l, ai, aj);
        gnn_msg<<<BN / 4, 256, 0, stream>>>(ai, aj, adj, sbuf, arow);
        gnn_lin2<4><<<BN / 4, 128, 0, stream>>>(hin, sbuf, arow, w2Tl, b2l, hout);
    }
}